// Round 1
// baseline (60.096 us; speedup 1.0000x reference)
//
#include <hip/hip_runtime.h>
#include <math.h>

#define SQRT2F 1.41421356237309504880f

// ndtri(p) for p in [1e-7, 1-1e-7], well-conditioned in both tails.
// p < 0.5:  z = -sqrt(2) * erfcinv(2p)          (2p exact)
// p >= 0.5: z = +sqrt(2) * erfcinv(2(1-p))      (1-p exact by Sterbenz for p in [0.5,1])
__device__ __forceinline__ float ndtri_f(float p) {
    float q = (p < 0.5f) ? (2.0f * p) : (2.0f * (1.0f - p));
    float r = SQRT2F * erfcinvf(q);
    return (p < 0.5f) ? -r : r;
}

__device__ __forceinline__ float elem(float uval, float cdfu, float u, bool is_c) {
    const float PLO = 1e-7f;
    const float PHI_ = 1.0f - 1e-7f;
    float p = fminf(fmaxf(uval * cdfu, PLO), PHI_);
    float z = ndtri_f(p);
    return is_c ? u : z;
}

__global__ __launch_bounds__(256) void MappingToContinuous_kernel(
    const int* __restrict__ C,       // [B*N]
    const float* __restrict__ eps,   // [B*N]
    const float4* __restrict__ U,    // [B*N*K/4]
    float4* __restrict__ out,        // [B*N*K/4]
    int total4)
{
    int stride = gridDim.x * blockDim.x;
    for (int i = blockIdx.x * blockDim.x + threadIdx.x; i < total4; i += stride) {
        int row = i >> 5;            // K=128 -> 32 float4 per row
        int k0  = (i & 31) << 2;     // starting k of this float4
        float u = eps[row];
        float cdfu = normcdff(u);    // Phi(u)
        int c = C[row];
        float4 uv = U[i];
        float4 r;
        r.x = elem(uv.x, cdfu, u, (k0 + 0) == c);
        r.y = elem(uv.y, cdfu, u, (k0 + 1) == c);
        r.z = elem(uv.z, cdfu, u, (k0 + 2) == c);
        r.w = elem(uv.w, cdfu, u, (k0 + 3) == c);
        out[i] = r;
    }
}

extern "C" void kernel_launch(void* const* d_in, const int* in_sizes, int n_in,
                              void* d_out, int out_size, void* d_ws, size_t ws_size,
                              hipStream_t stream) {
    const int*   C   = (const int*)d_in[0];
    const float* eps = (const float*)d_in[1];
    const float4* U  = (const float4*)d_in[2];
    float4* out = (float4*)d_out;

    int total4 = out_size / 4;       // 33,554,432 / 4 = 8,388,608
    int block = 256;
    int grid = 4096;                 // grid-stride: 8 float4 per thread
    hipLaunchKernelGGL(MappingToContinuous_kernel, dim3(grid), dim3(block), 0, stream,
                       C, eps, U, out, total4);
}

// Round 2
// 59.656 us; speedup vs baseline: 1.0074x; 1.0074x over previous
//
#include <hip/hip_runtime.h>
#include <math.h>

#define SQRT2F 1.41421356237309504880f

// Fast ndtri(p) for p in [1e-7, 1-1e-7].
//   p < 0.5 : z = -sqrt2 * erfinv(1-2p),  q = 2p       (exact)
//   p >= 0.5: z = +sqrt2 * erfinv(2p-1),  q = 2(1-p)   (exact, Sterbenz)
// erfinv(x) with x = 1-q via Giles (GPU Gems-style), w computed directly
// from q so the tail stays well-conditioned: w = -log(q*(2-q)) = -log(1-x^2).
__device__ __forceinline__ float ndtri_fast(float p) {
    bool hi = p >= 0.5f;
    float q = 2.0f * (hi ? (1.0f - p) : p);   // (0, 1]
    float x = 1.0f - q;                       // erfinv argument, >= 0
    float y = q * (2.0f - q);                 // 1 - x^2, exact-ish from q
    float w = -__logf(y);                     // fast log (trans pipe)

    // central branch: t = w - 2.5
    float tc = w - 2.5f;
    float pc =  2.81022636e-08f;
    pc = fmaf(pc, tc,  3.43273939e-07f);
    pc = fmaf(pc, tc, -3.5233877e-06f);
    pc = fmaf(pc, tc, -4.39150654e-06f);
    pc = fmaf(pc, tc,  0.00021858087f);
    pc = fmaf(pc, tc, -0.00125372503f);
    pc = fmaf(pc, tc, -0.00417768164f);
    pc = fmaf(pc, tc,  0.246640727f);
    pc = fmaf(pc, tc,  1.50140941f);

    // tail branch: t = sqrt(w) - 3
    float tt = __fsqrt_rn(w) - 3.0f;
    float pt = -0.000200214257f;
    pt = fmaf(pt, tt,  0.000100950558f);
    pt = fmaf(pt, tt,  0.00134934322f);
    pt = fmaf(pt, tt, -0.00367342844f);
    pt = fmaf(pt, tt,  0.00573950773f);
    pt = fmaf(pt, tt, -0.0076224613f);
    pt = fmaf(pt, tt,  0.00943887047f);
    pt = fmaf(pt, tt,  1.00167406f);
    pt = fmaf(pt, tt,  2.83297682f);

    float pw = (w < 5.0f) ? pc : pt;
    float s  = hi ? SQRT2F : -SQRT2F;
    return pw * x * s;
}

__device__ __forceinline__ float elem(float uval, float cdfu, float u, bool is_c) {
    const float PLO  = 1e-7f;
    const float PHI_ = 1.0f - 1e-7f;
    float p = fminf(fmaxf(uval * cdfu, PLO), PHI_);
    float z = ndtri_fast(p);
    return is_c ? u : z;
}

__global__ __launch_bounds__(256) void MappingToContinuous_kernel(
    const int* __restrict__ C,       // [B*N]
    const float* __restrict__ eps,   // [B*N]
    const float4* __restrict__ U,    // [B*N*K/4]
    float4* __restrict__ out,        // [B*N*K/4]
    int total4)
{
    int stride = gridDim.x * blockDim.x;
    for (int i = blockIdx.x * blockDim.x + threadIdx.x; i < total4; i += stride) {
        int row = i >> 5;            // K=128 -> 32 float4 per row
        int k0  = (i & 31) << 2;     // starting k of this float4
        float u = eps[row];
        float cdfu = normcdff(u);    // Phi(u) — keep libm accuracy (amortized /4)
        int c = C[row];
        float4 uv = U[i];
        float4 r;
        r.x = elem(uv.x, cdfu, u, (k0 + 0) == c);
        r.y = elem(uv.y, cdfu, u, (k0 + 1) == c);
        r.z = elem(uv.z, cdfu, u, (k0 + 2) == c);
        r.w = elem(uv.w, cdfu, u, (k0 + 3) == c);
        out[i] = r;
    }
}

extern "C" void kernel_launch(void* const* d_in, const int* in_sizes, int n_in,
                              void* d_out, int out_size, void* d_ws, size_t ws_size,
                              hipStream_t stream) {
    const int*   C   = (const int*)d_in[0];
    const float* eps = (const float*)d_in[1];
    const float4* U  = (const float4*)d_in[2];
    float4* out = (float4*)d_out;

    int total4 = out_size / 4;       // 33,554,432 / 4 = 8,388,608
    int block = 256;
    int grid = 4096;                 // grid-stride: 8 float4 per thread
    hipLaunchKernelGGL(MappingToContinuous_kernel, dim3(grid), dim3(block), 0, stream,
                       C, eps, U, out, total4);
}

// Round 3
// 59.056 us; speedup vs baseline: 1.0176x; 1.0102x over previous
//
#include <hip/hip_runtime.h>
#include <math.h>

#define SQRT2F 1.41421356237309504880f

// Fast ndtri(p) for p in [1e-7, 1-1e-7].
//   p < 0.5 : z = -sqrt2 * erfinv(1-2p),  q = 2p       (exact)
//   p >= 0.5: z = +sqrt2 * erfinv(2p-1),  q = 2(1-p)   (exact, Sterbenz)
// erfinv via Giles-style branchless polys; w = -log(q*(2-q)) stays
// well-conditioned in the tail because it is computed from exact q.
__device__ __forceinline__ float ndtri_fast(float p) {
    bool hi = p >= 0.5f;
    float q = 2.0f * (hi ? (1.0f - p) : p);   // (0, 1]
    float x = 1.0f - q;                       // erfinv argument, >= 0
    float y = q * (2.0f - q);                 // 1 - x^2
    float w = -__logf(y);

    // central branch: t = w - 2.5
    float tc = w - 2.5f;
    float pc =  2.81022636e-08f;
    pc = fmaf(pc, tc,  3.43273939e-07f);
    pc = fmaf(pc, tc, -3.5233877e-06f);
    pc = fmaf(pc, tc, -4.39150654e-06f);
    pc = fmaf(pc, tc,  0.00021858087f);
    pc = fmaf(pc, tc, -0.00125372503f);
    pc = fmaf(pc, tc, -0.00417768164f);
    pc = fmaf(pc, tc,  0.246640727f);
    pc = fmaf(pc, tc,  1.50140941f);

    // tail branch: t = sqrt(w) - 3
    float tt = __fsqrt_rn(w) - 3.0f;
    float pt = -0.000200214257f;
    pt = fmaf(pt, tt,  0.000100950558f);
    pt = fmaf(pt, tt,  0.00134934322f);
    pt = fmaf(pt, tt, -0.00367342844f);
    pt = fmaf(pt, tt,  0.00573950773f);
    pt = fmaf(pt, tt, -0.0076224613f);
    pt = fmaf(pt, tt,  0.00943887047f);
    pt = fmaf(pt, tt,  1.00167406f);
    pt = fmaf(pt, tt,  2.83297682f);

    float pw = (w < 5.0f) ? pc : pt;
    float s  = hi ? SQRT2F : -SQRT2F;
    return pw * x * s;
}

__device__ __forceinline__ float elem(float uval, float cdfu, float u, bool is_c) {
    const float PLO  = 1e-7f;
    const float PHI_ = 1.0f - 1e-7f;
    float p = fminf(fmaxf(uval * cdfu, PLO), PHI_);
    float z = ndtri_fast(p);
    return is_c ? u : z;
}

// Pre-kernel: cdfu[row] = Phi(eps[row]). 262,144 rows -> ~0.5 us of VALU.
__global__ __launch_bounds__(256) void phi_kernel(
    const float* __restrict__ eps, float* __restrict__ cdfu, int n)
{
    int i = blockIdx.x * blockDim.x + threadIdx.x;
    if (i < n) cdfu[i] = normcdff(eps[i]);
}

template <bool USE_WS>
__global__ __launch_bounds__(256) void MappingToContinuous_kernel(
    const int* __restrict__ C,        // [B*N]
    const float* __restrict__ eps,    // [B*N]
    const float* __restrict__ cdfu_t, // [B*N] precomputed Phi(eps) (if USE_WS)
    const float4* __restrict__ U,     // [B*N*K/4]
    float4* __restrict__ out,         // [B*N*K/4]
    int total4)
{
    int stride = gridDim.x * blockDim.x;
    for (int i = blockIdx.x * blockDim.x + threadIdx.x; i < total4; i += stride) {
        int row = i >> 5;            // K=128 -> 32 float4 per row
        int k0  = (i & 31) << 2;     // starting k of this float4
        float u = eps[row];          // 32 lanes same addr -> broadcast
        float cdfu = USE_WS ? cdfu_t[row] : normcdff(u);
        int c = C[row];
        float4 uv = U[i];
        float4 r;
        r.x = elem(uv.x, cdfu, u, (k0 + 0) == c);
        r.y = elem(uv.y, cdfu, u, (k0 + 1) == c);
        r.z = elem(uv.z, cdfu, u, (k0 + 2) == c);
        r.w = elem(uv.w, cdfu, u, (k0 + 3) == c);
        out[i] = r;
    }
}

extern "C" void kernel_launch(void* const* d_in, const int* in_sizes, int n_in,
                              void* d_out, int out_size, void* d_ws, size_t ws_size,
                              hipStream_t stream) {
    const int*   C   = (const int*)d_in[0];
    const float* eps = (const float*)d_in[1];
    const float4* U  = (const float4*)d_in[2];
    float4* out = (float4*)d_out;

    int nrows  = in_sizes[1];            // B*N = 262,144
    int total4 = out_size / 4;           // 8,388,608 float4
    int block = 256;
    int grid = 4096;

    size_t ws_needed = (size_t)nrows * sizeof(float);
    if (ws_size >= ws_needed) {
        float* cdfu = (float*)d_ws;
        hipLaunchKernelGGL(phi_kernel, dim3((nrows + block - 1) / block), dim3(block),
                           0, stream, eps, cdfu, nrows);
        hipLaunchKernelGGL((MappingToContinuous_kernel<true>), dim3(grid), dim3(block),
                           0, stream, C, eps, cdfu, U, out, total4);
    } else {
        hipLaunchKernelGGL((MappingToContinuous_kernel<false>), dim3(grid), dim3(block),
                           0, stream, C, eps, (const float*)nullptr, U, out, total4);
    }
}

// Round 4
// 51.157 us; speedup vs baseline: 1.1747x; 1.1544x over previous
//
#include <hip/hip_runtime.h>
#include <math.h>

#define SQRT2F 1.41421356237309504880f

// Fast ndtri(p) for p in [1e-7, 1-1e-7].
//   p < 0.5 : z = -sqrt2 * erfinv(1-2p),  q = 2p       (exact)
//   p >= 0.5: z = +sqrt2 * erfinv(2p-1),  q = 2(1-p)   (exact, Sterbenz)
// erfinv via Giles-style polys; w = -log(q*(2-q)) is computed from exact q so
// the tail stays well-conditioned. Tail poly (w>=5, ~0.8% of lanes) is skipped
// when no lane in the wave needs it.
__device__ __forceinline__ float ndtri_fast(float p) {
    bool hi = p >= 0.5f;
    float q = 2.0f * (hi ? (1.0f - p) : p);   // (0, 1]
    float x = 1.0f - q;                       // erfinv argument, >= 0
    float y = q * (2.0f - q);                 // 1 - x^2
    float w = -__logf(y);

    // central branch: t = w - 2.5
    float tc = w - 2.5f;
    float pw =  2.81022636e-08f;
    pw = fmaf(pw, tc,  3.43273939e-07f);
    pw = fmaf(pw, tc, -3.5233877e-06f);
    pw = fmaf(pw, tc, -4.39150654e-06f);
    pw = fmaf(pw, tc,  0.00021858087f);
    pw = fmaf(pw, tc, -0.00125372503f);
    pw = fmaf(pw, tc, -0.00417768164f);
    pw = fmaf(pw, tc,  0.246640727f);
    pw = fmaf(pw, tc,  1.50140941f);

    if (__builtin_expect(__any(w >= 5.0f), 0)) {
        // tail branch: t = sqrt(w) - 3
        float tt = __fsqrt_rn(w) - 3.0f;
        float pt = -0.000200214257f;
        pt = fmaf(pt, tt,  0.000100950558f);
        pt = fmaf(pt, tt,  0.00134934322f);
        pt = fmaf(pt, tt, -0.00367342844f);
        pt = fmaf(pt, tt,  0.00573950773f);
        pt = fmaf(pt, tt, -0.0076224613f);
        pt = fmaf(pt, tt,  0.00943887047f);
        pt = fmaf(pt, tt,  1.00167406f);
        pt = fmaf(pt, tt,  2.83297682f);
        pw = (w < 5.0f) ? pw : pt;
    }
    float s = hi ? SQRT2F : -SQRT2F;
    return pw * x * s;
}

__device__ __forceinline__ float elem(float uval, float cdfu, float u, bool is_c) {
    const float PLO  = 1e-7f;
    const float PHI_ = 1.0f - 1e-7f;
    float p = fminf(fmaxf(uval * cdfu, PLO), PHI_);
    float z = ndtri_fast(p);
    return is_c ? u : z;
}

__device__ __forceinline__ float4 quad(float4 uv, float cdfu, float u, int k0, int c) {
    float4 r;
    r.x = elem(uv.x, cdfu, u, (k0 + 0) == c);
    r.y = elem(uv.y, cdfu, u, (k0 + 1) == c);
    r.z = elem(uv.z, cdfu, u, (k0 + 2) == c);
    r.w = elem(uv.w, cdfu, u, (k0 + 3) == c);
    return r;
}

// Pre-kernel: cdfu[row] = Phi(eps[row]).
__global__ __launch_bounds__(256) void phi_kernel(
    const float* __restrict__ eps, float* __restrict__ cdfu, int n)
{
    int i = blockIdx.x * blockDim.x + threadIdx.x;
    if (i < n) cdfu[i] = normcdff(eps[i]);
}

// Each block owns 1024 consecutive float4 (4096 elems = 32 rows).
// Each thread: 4 float4 at +0,+256,+512,+768 — all loads issued up front
// (4 dwordx4 + 12 broadcast dwords outstanding) for latency hiding.
template <bool USE_WS>
__global__ __launch_bounds__(256) void MappingToContinuous_kernel(
    const int* __restrict__ C,        // [B*N]
    const float* __restrict__ eps,    // [B*N]
    const float* __restrict__ cdfu_t, // [B*N]
    const float4* __restrict__ U,     // [B*N*K/4]
    float4* __restrict__ out)         // [B*N*K/4]
{
    int i0 = blockIdx.x * 1024 + threadIdx.x;
    int i1 = i0 + 256, i2 = i0 + 512, i3 = i0 + 768;

    float4 u0 = U[i0], u1 = U[i1], u2 = U[i2], u3 = U[i3];

    int r0 = i0 >> 5, r1 = i1 >> 5, r2 = i2 >> 5, r3 = i3 >> 5;
    float e0 = eps[r0], e1 = eps[r1], e2 = eps[r2], e3 = eps[r3];
    float f0 = USE_WS ? cdfu_t[r0] : normcdff(e0);
    float f1 = USE_WS ? cdfu_t[r1] : normcdff(e1);
    float f2 = USE_WS ? cdfu_t[r2] : normcdff(e2);
    float f3 = USE_WS ? cdfu_t[r3] : normcdff(e3);
    int c0 = C[r0], c1 = C[r1], c2 = C[r2], c3 = C[r3];

    out[i0] = quad(u0, f0, e0, (i0 & 31) << 2, c0);
    out[i1] = quad(u1, f1, e1, (i1 & 31) << 2, c1);
    out[i2] = quad(u2, f2, e2, (i2 & 31) << 2, c2);
    out[i3] = quad(u3, f3, e3, (i3 & 31) << 2, c3);
}

extern "C" void kernel_launch(void* const* d_in, const int* in_sizes, int n_in,
                              void* d_out, int out_size, void* d_ws, size_t ws_size,
                              hipStream_t stream) {
    const int*   C   = (const int*)d_in[0];
    const float* eps = (const float*)d_in[1];
    const float4* U  = (const float4*)d_in[2];
    float4* out = (float4*)d_out;

    int nrows  = in_sizes[1];            // B*N = 262,144
    int total4 = out_size / 4;           // 8,388,608 float4
    int grid   = total4 / 1024;          // 8192 blocks, exact

    size_t ws_needed = (size_t)nrows * sizeof(float);
    if (ws_size >= ws_needed) {
        float* cdfu = (float*)d_ws;
        hipLaunchKernelGGL(phi_kernel, dim3((nrows + 255) / 256), dim3(256),
                           0, stream, eps, cdfu, nrows);
        hipLaunchKernelGGL((MappingToContinuous_kernel<true>), dim3(grid), dim3(256),
                           0, stream, C, eps, cdfu, U, out);
    } else {
        hipLaunchKernelGGL((MappingToContinuous_kernel<false>), dim3(grid), dim3(256),
                           0, stream, C, eps, (const float*)nullptr, U, out);
    }
}

// Round 6
// 49.439 us; speedup vs baseline: 1.2156x; 1.0347x over previous
//
#include <hip/hip_runtime.h>
#include <math.h>

typedef float f32x4 __attribute__((ext_vector_type(4)));

// Branchless ndtri(p) for p in [1e-7, 1-1e-7] via Abramowitz-Stegun 26.2.23:
//   t = sqrt(-2 ln p'), z = +/- (t - (c0+c1 t+c2 t^2)/(1+d1 t+d2 t^2+d3 t^3))
// |err| < 4.5e-4 absolute, uniformly — far under the 0.104 threshold.
// p' = p (lo) or 1-p (hi, Sterbenz-exact) keeps both tails well-conditioned.
__device__ __forceinline__ float ndtri_as(float p) {
    bool hi = p >= 0.5f;
    float pp = hi ? (1.0f - p) : p;                 // (0, 0.5]
    // t = sqrt(-2 ln pp) = sqrt(-2 ln2 * log2 pp)
    float t = __fsqrt_rn(-1.38629436112f * __log2f(pp));
    float num = fmaf(fmaf(0.010328f, t, 0.802853f), t, 2.515517f);
    float den = fmaf(fmaf(fmaf(0.001308f, t, 0.189269f), t, 1.432788f), t, 1.0f);
    float z = t - num * __builtin_amdgcn_rcpf(den); // v_rcp_f32, ~1 ulp
    return hi ? z : -z;
}

__device__ __forceinline__ float elem(float uval, float cdfu, float u, bool is_c) {
    const float PLO  = 1e-7f;
    const float PHI_ = 1.0f - 1e-7f;
    float p = fminf(fmaxf(uval * cdfu, PLO), PHI_);
    float z = ndtri_as(p);
    return is_c ? u : z;
}

__device__ __forceinline__ f32x4 quad(f32x4 uv, float cdfu, float u, int k0, int c) {
    f32x4 r;
    r.x = elem(uv.x, cdfu, u, (k0 + 0) == c);
    r.y = elem(uv.y, cdfu, u, (k0 + 1) == c);
    r.z = elem(uv.z, cdfu, u, (k0 + 2) == c);
    r.w = elem(uv.w, cdfu, u, (k0 + 3) == c);
    return r;
}

// Pre-kernel: cdfu[row] = Phi(eps[row]).
__global__ __launch_bounds__(256) void phi_kernel(
    const float* __restrict__ eps, float* __restrict__ cdfu, int n)
{
    int i = blockIdx.x * blockDim.x + threadIdx.x;
    if (i < n) cdfu[i] = normcdff(eps[i]);
}

// Each block owns 1024 consecutive float4 (32 rows). Each thread: 4 float4 at
// +0,+256,+512,+768 — all loads issued up front for latency hiding.
// Stores are non-temporal: out is never re-read, keep U resident in L3.
template <bool USE_WS>
__global__ __launch_bounds__(256) void MappingToContinuous_kernel(
    const int* __restrict__ C,        // [B*N]
    const float* __restrict__ eps,    // [B*N]
    const float* __restrict__ cdfu_t, // [B*N]
    const f32x4* __restrict__ U,      // [B*N*K/4]
    f32x4* __restrict__ out)          // [B*N*K/4]
{
    int i0 = blockIdx.x * 1024 + threadIdx.x;
    int i1 = i0 + 256, i2 = i0 + 512, i3 = i0 + 768;

    f32x4 u0 = U[i0], u1 = U[i1], u2 = U[i2], u3 = U[i3];

    int r0 = i0 >> 5, r1 = i1 >> 5, r2 = i2 >> 5, r3 = i3 >> 5;
    float e0 = eps[r0], e1 = eps[r1], e2 = eps[r2], e3 = eps[r3];
    float f0 = USE_WS ? cdfu_t[r0] : normcdff(e0);
    float f1 = USE_WS ? cdfu_t[r1] : normcdff(e1);
    float f2 = USE_WS ? cdfu_t[r2] : normcdff(e2);
    float f3 = USE_WS ? cdfu_t[r3] : normcdff(e3);
    int c0 = C[r0], c1 = C[r1], c2 = C[r2], c3 = C[r3];

    f32x4 o0 = quad(u0, f0, e0, (i0 & 31) << 2, c0);
    f32x4 o1 = quad(u1, f1, e1, (i1 & 31) << 2, c1);
    f32x4 o2 = quad(u2, f2, e2, (i2 & 31) << 2, c2);
    f32x4 o3 = quad(u3, f3, e3, (i3 & 31) << 2, c3);

    __builtin_nontemporal_store(o0, &out[i0]);
    __builtin_nontemporal_store(o1, &out[i1]);
    __builtin_nontemporal_store(o2, &out[i2]);
    __builtin_nontemporal_store(o3, &out[i3]);
}

extern "C" void kernel_launch(void* const* d_in, const int* in_sizes, int n_in,
                              void* d_out, int out_size, void* d_ws, size_t ws_size,
                              hipStream_t stream) {
    const int*   C   = (const int*)d_in[0];
    const float* eps = (const float*)d_in[1];
    const f32x4* U   = (const f32x4*)d_in[2];
    f32x4* out = (f32x4*)d_out;

    int nrows  = in_sizes[1];            // B*N = 262,144
    int total4 = out_size / 4;           // 8,388,608 float4
    int grid   = total4 / 1024;          // 8192 blocks, exact

    size_t ws_needed = (size_t)nrows * sizeof(float);
    if (ws_size >= ws_needed) {
        float* cdfu = (float*)d_ws;
        hipLaunchKernelGGL(phi_kernel, dim3((nrows + 255) / 256), dim3(256),
                           0, stream, eps, cdfu, nrows);
        hipLaunchKernelGGL((MappingToContinuous_kernel<true>), dim3(grid), dim3(256),
                           0, stream, C, eps, cdfu, U, out);
    } else {
        hipLaunchKernelGGL((MappingToContinuous_kernel<false>), dim3(grid), dim3(256),
                           0, stream, C, eps, (const float*)nullptr, U, out);
    }
}

// Round 7
// 45.772 us; speedup vs baseline: 1.3129x; 1.0801x over previous
//
#include <hip/hip_runtime.h>
#include <math.h>

typedef float f32x4 __attribute__((ext_vector_type(4)));

// Branchless ndtri(p) for p in [1e-7, 1-1e-7] via Abramowitz-Stegun 26.2.23:
//   t = sqrt(-2 ln p'), z = +/- (t - (c0+c1 t+c2 t^2)/(1+d1 t+d2 t^2+d3 t^3))
// |err| < 4.5e-4 absolute, uniformly. p' = p or (1-p) (Sterbenz-exact).
__device__ __forceinline__ float ndtri_as(float p) {
    bool hi = p >= 0.5f;
    float pp = hi ? (1.0f - p) : p;                 // (0, 0.5]
    float t = __fsqrt_rn(-1.38629436112f * __log2f(pp)); // sqrt(-2 ln pp)
    float num = fmaf(fmaf(0.010328f, t, 0.802853f), t, 2.515517f);
    float den = fmaf(fmaf(fmaf(0.001308f, t, 0.189269f), t, 1.432788f), t, 1.0f);
    float z = t - num * __builtin_amdgcn_rcpf(den);
    return hi ? z : -z;
}

__device__ __forceinline__ float elem(float uval, float cdfu, float u, bool is_c) {
    const float PLO  = 1e-7f;
    const float PHI_ = 1.0f - 1e-7f;
    float p = fminf(fmaxf(uval * cdfu, PLO), PHI_);
    float z = ndtri_as(p);
    return is_c ? u : z;
}

__device__ __forceinline__ f32x4 quad(f32x4 uv, float cdfu, float u, int k0, int c) {
    f32x4 r;
    r.x = elem(uv.x, cdfu, u, (k0 + 0) == c);
    r.y = elem(uv.y, cdfu, u, (k0 + 1) == c);
    r.z = elem(uv.z, cdfu, u, (k0 + 2) == c);
    r.w = elem(uv.w, cdfu, u, (k0 + 3) == c);
    return r;
}

// One fused kernel. Block = 256 threads owns 2048 consecutive float4 = 64 rows.
// 1) all 8 U-loads issued at entry (stay in flight across the barrier —
//    register-destined loads only need vmcnt before first use)
// 2) wave 0 computes Phi(eps) for the 64 rows into LDS under the load shadow
// 3) barrier, then 8x (compute quad, nontemporal store)
__global__ __launch_bounds__(256) void MappingToContinuous_kernel(
    const int* __restrict__ C,      // [B*N]
    const float* __restrict__ eps,  // [B*N]
    const f32x4* __restrict__ U,    // [B*N*K/4]
    f32x4* __restrict__ out)        // [B*N*K/4]
{
    __shared__ float e_s[64];
    __shared__ float f_s[64];
    __shared__ int   c_s[64];

    int t  = threadIdx.x;
    int i0 = blockIdx.x * 2048 + t;

    f32x4 u0 = U[i0];
    f32x4 u1 = U[i0 +  256];
    f32x4 u2 = U[i0 +  512];
    f32x4 u3 = U[i0 +  768];
    f32x4 u4 = U[i0 + 1024];
    f32x4 u5 = U[i0 + 1280];
    f32x4 u6 = U[i0 + 1536];
    f32x4 u7 = U[i0 + 1792];

    int row0 = blockIdx.x * 64;
    if (t < 64) {
        float e = eps[row0 + t];
        e_s[t] = e;
        f_s[t] = normcdff(e);   // libm accuracy, hidden under U-load latency
        c_s[t] = C[row0 + t];
    }
    __syncthreads();

    int lr = t >> 5;            // local row of quad k is lr + 8k
    int k0 = (t & 31) << 2;     // k-offset within row (same for all 8 quads)

    f32x4 o;
    o = quad(u0, f_s[lr +  0], e_s[lr +  0], k0, c_s[lr +  0]);
    __builtin_nontemporal_store(o, &out[i0]);
    o = quad(u1, f_s[lr +  8], e_s[lr +  8], k0, c_s[lr +  8]);
    __builtin_nontemporal_store(o, &out[i0 +  256]);
    o = quad(u2, f_s[lr + 16], e_s[lr + 16], k0, c_s[lr + 16]);
    __builtin_nontemporal_store(o, &out[i0 +  512]);
    o = quad(u3, f_s[lr + 24], e_s[lr + 24], k0, c_s[lr + 24]);
    __builtin_nontemporal_store(o, &out[i0 +  768]);
    o = quad(u4, f_s[lr + 32], e_s[lr + 32], k0, c_s[lr + 32]);
    __builtin_nontemporal_store(o, &out[i0 + 1024]);
    o = quad(u5, f_s[lr + 40], e_s[lr + 40], k0, c_s[lr + 40]);
    __builtin_nontemporal_store(o, &out[i0 + 1280]);
    o = quad(u6, f_s[lr + 48], e_s[lr + 48], k0, c_s[lr + 48]);
    __builtin_nontemporal_store(o, &out[i0 + 1536]);
    o = quad(u7, f_s[lr + 56], e_s[lr + 56], k0, c_s[lr + 56]);
    __builtin_nontemporal_store(o, &out[i0 + 1792]);
}

extern "C" void kernel_launch(void* const* d_in, const int* in_sizes, int n_in,
                              void* d_out, int out_size, void* d_ws, size_t ws_size,
                              hipStream_t stream) {
    const int*   C   = (const int*)d_in[0];
    const float* eps = (const float*)d_in[1];
    const f32x4* U   = (const f32x4*)d_in[2];
    f32x4* out = (f32x4*)d_out;

    int total4 = out_size / 4;           // 8,388,608 float4
    int grid   = total4 / 2048;          // 4096 blocks, exact (64 rows each)

    hipLaunchKernelGGL(MappingToContinuous_kernel, dim3(grid), dim3(256),
                       0, stream, C, eps, U, out);
}